// Round 1
// 559.823 us; speedup vs baseline: 1.0682x; 1.0682x over previous
//
#include <hip/hip_runtime.h>

// ---------------------------------------------------------------------------
// PatchTransformerMSG fused kernel for MI355X (gfx950)
// B=16, S=4096 -> 65536 tokens; D=384; POS_HID=128.
// Chain: pos_emb -> h -> {q,k,v} -> gate -> softmax(row) -> res
// One WG per 32-token tile (TM=32: halves LDS vs TM=64 so 2 WGs fit per CU,
// doubling occupancy 23%->~46% -- the chain is fully row-independent so the
// tile height is free). Whole chain fused; activations in LDS; weights
// pre-packed to MFMA B-frag order in d_ws. Runtime dtype probe (bf16 vs f32)
// selects load/store paths; MFMA core always bf16.
// ---------------------------------------------------------------------------

#define NTOK   65536
#define DIMS   384
#define XC     387          // x row stride (3 centroid + 384 patch)
#define TM     32           // tokens per workgroup (32 -> 50.8KB LDS -> 2 WG/CU)
#define LDP    392          // padded LDS stride (rows 16B-aligned, 2-way-bank only)
#define PHP    136          // padded LDS stride for 128-wide posh tile
#define SCALE  0.051031036307982884f   // 384^-0.5
#define WS_WEIGHT_ELEMS 1081344        // packed-weight ushort count
#define WS_FLAG_OFF     (WS_WEIGHT_ELEMS)   // flag stored as int at ushort idx (8B aligned)

typedef __bf16 bf16x8 __attribute__((ext_vector_type(8)));
typedef float  floatx4 __attribute__((ext_vector_type(4)));

__device__ __forceinline__ float bf2f(ushort u) {
    return __uint_as_float(((unsigned)u) << 16);
}
__device__ __forceinline__ ushort f2bf(float f) {
    unsigned u = __float_as_uint(f);
    unsigned r = (u + 0x7FFFu + ((u >> 16) & 1u)) >> 16;   // RNE
    return (ushort)r;
}
__device__ __forceinline__ float gelu_f(float v) {
    return 0.5f * v * (1.0f + erff(v * 0.70710678118654752f));
}
// dual-dtype element load/store (flag is wave-uniform)
__device__ __forceinline__ float ldg(const void* p, size_t i, int isbf) {
    return isbf ? bf2f(((const ushort*)p)[i]) : ((const float*)p)[i];
}
__device__ __forceinline__ void stg(void* p, size_t i, float v, int isbf) {
    if (isbf) ((ushort*)p)[i] = f2bf(v);
    else      ((float*)p)[i]  = v;
}

// ---------------------------------------------------------------------------
// dtype probe: look at low u16 of x's first 256 dwords. bf16 data -> valid
// Gaussian bf16 (exp field in [90,141] or 0). f32 data -> random mantissa
// bits (uniform exp field). flag=1 -> bf16, flag=0 -> f32.
// ---------------------------------------------------------------------------
__global__ void detect_dtype(const ushort* x, int* flag) {
    int ok = 1;
    for (int i = threadIdx.x; i < 256; i += 64) {
        ushort u = x[2 * i];
        int e = (u >> 7) & 0xFF;
        if (!(e == 0 || (e >= 90 && e <= 141))) ok = 0;
    }
    unsigned long long m = __ballot(ok);
    if (threadIdx.x == 0) *flag = (m == ~0ULL) ? 1 : 0;
}

// ---------------------------------------------------------------------------
// Weight repack: W (K x 384 row-major) -> MFMA B-fragments: quanta idx =
// (nt*KT + kt)*64 + lane, 8 bf16/lane, lane holds
// B[k = kt*32 + (lane>>4)*8 + j][n = nt*16 + (lane&15)].
// ws elem offsets: pos2 @0 (49152), then 7x 147456: in,q,k,v,g1,g2,out.
// ---------------------------------------------------------------------------
__global__ void prep_weights(
    const void* __restrict__ Wpos2, const void* __restrict__ Win,
    const void* __restrict__ Wq,    const void* __restrict__ Wk,
    const void* __restrict__ Wv,    const void* __restrict__ Wg1,
    const void* __restrict__ Wg2,   const void* __restrict__ Wo,
    ushort* __restrict__ ws, const int* __restrict__ flagp)
{
    const int isbf = *flagp;
    const int nt   = blockIdx.x;   // 0..23
    const int y    = blockIdx.y;   // 0..87  (4 kt for pos2 + 7*12 kt)
    const int lane = threadIdx.x;  // 0..63
    const void* src;
    int kt, KT; size_t dstoff;
    if (y < 4) { src = Wpos2; KT = 4; kt = y; dstoff = 0; }
    else {
        int wi = (y - 4) / 12; kt = (y - 4) % 12; KT = 12;
        const void* tab[7] = {Win, Wq, Wk, Wv, Wg1, Wg2, Wo};
        src = tab[wi];
        dstoff = 49152 + (size_t)wi * 147456;
    }
    const int k = kt * 32 + (lane >> 4) * 8;
    const int n = nt * 16 + (lane & 15);
    ushort* dst = ws + dstoff + ((size_t)(nt * KT + kt) * 64 + lane) * 8;
    if (isbf) {
        const ushort* s16 = (const ushort*)src;
#pragma unroll
        for (int j = 0; j < 8; ++j) dst[j] = s16[(size_t)(k + j) * 384 + n];
    } else {
        const float* s32 = (const float*)src;
#pragma unroll
        for (int j = 0; j < 8; ++j) dst[j] = f2bf(s32[(size_t)(k + j) * 384 + n]);
    }
}

// ---------------------------------------------------------------------------
// Per-wave GEMM: C[32 x 48-strip] += A(LDS) @ Wpacked.  2 mtiles x 3 ntiles.
// A-frag: lane reads A[mt*16+(lane&15)][kt*32 + quad*8 .. +8] (ds_read_b128)
// B-frag: one global_load_dwordx4 per lane from packed weights.
// ---------------------------------------------------------------------------
template<int KT, int LDA>
__device__ __forceinline__ void gemm_acc(const ushort* sA, const bf16x8* wq,
                                         int ntBase, int lane, floatx4 acc[2][3])
{
    const int l16 = lane & 15, quad = lane >> 4;
#pragma unroll
    for (int kt = 0; kt < KT; ++kt) {
        const int k = kt * 32 + quad * 8;
        bf16x8 a[2];
#pragma unroll
        for (int mt = 0; mt < 2; ++mt)
            a[mt] = *reinterpret_cast<const bf16x8*>(sA + (mt * 16 + l16) * LDA + k);
        bf16x8 b[3];
#pragma unroll
        for (int i = 0; i < 3; ++i)
            b[i] = wq[((size_t)(ntBase + i) * KT + kt) * 64 + lane];
#pragma unroll
        for (int mt = 0; mt < 2; ++mt)
#pragma unroll
            for (int i = 0; i < 3; ++i)
                acc[mt][i] = __builtin_amdgcn_mfma_f32_16x16x32_bf16(a[mt], b[i], acc[mt][i], 0, 0, 0);
    }
}

__device__ __forceinline__ void zero_acc(floatx4 acc[2][3]) {
#pragma unroll
    for (int mt = 0; mt < 2; ++mt)
#pragma unroll
        for (int i = 0; i < 3; ++i)
            acc[mt][i] = (floatx4){0.f, 0.f, 0.f, 0.f};
}

__device__ __forceinline__ void bias_acc(floatx4 acc[2][3], const void* b,
                                         int ntBase, int l16, int isbf) {
#pragma unroll
    for (int i = 0; i < 3; ++i) {
        float bv = ldg(b, (ntBase + i) * 16 + l16, isbf);
#pragma unroll
        for (int mt = 0; mt < 2; ++mt) acc[mt][i] = (floatx4){bv, bv, bv, bv};
    }
}

// C/D layout: col = lane&15, row = quad*4 + reg  (m89/m91 verified)
__device__ __forceinline__ void store_lds(ushort* buf, floatx4 acc[2][3],
                                          int quad, int l16, int ntBase, bool dog) {
#pragma unroll
    for (int mt = 0; mt < 2; ++mt)
#pragma unroll
        for (int i = 0; i < 3; ++i)
#pragma unroll
            for (int r = 0; r < 4; ++r) {
                int rowl = mt * 16 + quad * 4 + r;
                int col  = (ntBase + i) * 16 + l16;
                float v = acc[mt][i][r];
                if (dog) v = gelu_f(v);
                buf[rowl * LDP + col] = f2bf(v);
            }
}

__global__ __launch_bounds__(512, 4) void fused_kernel(
    const void* __restrict__ x,
    const void* __restrict__ Wpos1, const void* __restrict__ bpos1,
    const void* __restrict__ bpos2, const void* __restrict__ bin,
    const void* __restrict__ bg1,   const void* __restrict__ bg2,
    const void* __restrict__ bout,
    const ushort* __restrict__ wpack,
    void* __restrict__ out, const int* __restrict__ flagp)
{
    __shared__ __align__(16) ushort bufA[TM * LDP];   // pre -> h -> g1 -> pv
    __shared__ __align__(16) ushort bufB[TM * LDP];   // posh(PHP) -> k -> d
    __shared__ float  cent[TM * 4];
    __shared__ float  rowsum[TM];

    const int isbf   = *flagp;
    const int tid    = (int)threadIdx.x;
    const int lane   = tid & 63;
    const int w      = tid >> 6;        // wave 0..7, owns cols [w*48, w*48+48)
    const int l16    = lane & 15;
    const int quad   = lane >> 4;
    const int ntBase = w * 3;
    const int row0   = (int)blockIdx.x * TM;

    const bf16x8* wq      = reinterpret_cast<const bf16x8*>(wpack);
    const bf16x8* wq_pos2 = wq;            // quanta (16B) offsets
    const bf16x8* wq_in   = wq + 6144;
    const bf16x8* wq_q    = wq + 24576;
    const bf16x8* wq_k    = wq + 43008;
    const bf16x8* wq_v    = wq + 61440;
    const bf16x8* wq_g1   = wq + 79872;
    const bf16x8* wq_g2   = wq + 98304;
    const bf16x8* wq_o    = wq + 116736;

    // ---- stage 0: load pre tile -> bufA, centroid -> cent, zero rowsum ----
    if (isbf) {
        const ushort* xp = (const ushort*)x;
        for (int idx = tid; idx < TM * DIMS; idx += 512) {
            int m = idx / DIMS, c = idx - m * DIMS;
            bufA[m * LDP + c] = xp[(size_t)(row0 + m) * XC + 3 + c];
        }
    } else {
        const float* xp = (const float*)x;
        for (int idx = tid; idx < TM * DIMS; idx += 512) {
            int m = idx / DIMS, c = idx - m * DIMS;
            bufA[m * LDP + c] = f2bf(xp[(size_t)(row0 + m) * XC + 3 + c]);
        }
    }
    if (tid < TM * 3) {
        int m = tid / 3, j = tid - m * 3;
        cent[m * 4 + j] = ldg(x, (size_t)(row0 + m) * XC + j, isbf);
    }
    if (tid < TM) rowsum[tid] = 0.f;
    __syncthreads();

    // ---- stage 1: posh = gelu(centroid @ Wpos1 + bpos1) -> bufB (PHP) ----
    for (int idx = tid; idx < TM * 128; idx += 512) {
        int m = idx >> 7, c = idx & 127;
        float a = ldg(bpos1, c, isbf)
                + cent[m * 4 + 0] * ldg(Wpos1, c,       isbf)
                + cent[m * 4 + 1] * ldg(Wpos1, 128 + c, isbf)
                + cent[m * 4 + 2] * ldg(Wpos1, 256 + c, isbf);
        bufB[m * PHP + c] = f2bf(gelu_f(a));
    }
    __syncthreads();

    floatx4 acc[2][3];

    // ---- stage 2: h = pre@Win + posh@Wpos2 + (bin + bpos2) -> bufA ----
#pragma unroll
    for (int mt = 0; mt < 2; ++mt)
#pragma unroll
        for (int i = 0; i < 3; ++i) {
            int col = (ntBase + i) * 16 + l16;
            float bv = ldg(bin, col, isbf) + ldg(bpos2, col, isbf);
            acc[mt][i] = (floatx4){bv, bv, bv, bv};
        }
    gemm_acc<12, LDP>(bufA, wq_in,   ntBase, lane, acc);
    gemm_acc<4,  PHP>(bufB, wq_pos2, ntBase, lane, acc);
    __syncthreads();                       // all waves done reading pre/posh
    store_lds(bufA, acc, quad, l16, ntBase, false);
    __syncthreads();

    // ---- stage 3: k = h@Wk -> bufB ----
    zero_acc(acc);
    gemm_acc<12, LDP>(bufA, wq_k, ntBase, lane, acc);
    store_lds(bufB, acc, quad, l16, ntBase, false);   // bufB has no readers now
    __syncthreads();

    // ---- stage 4: q = h@Wq -> global; d = q - k -> bufB (in place) ----
    zero_acc(acc);
    gemm_acc<12, LDP>(bufA, wq_q, ntBase, lane, acc);
#pragma unroll
    for (int mt = 0; mt < 2; ++mt)
#pragma unroll
        for (int i = 0; i < 3; ++i)
#pragma unroll
            for (int r = 0; r < 4; ++r) {
                int rowl = mt * 16 + quad * 4 + r;
                int col  = (ntBase + i) * 16 + l16;
                float qv = acc[mt][i][r];
                stg(out, (size_t)(row0 + rowl) * DIMS + col, qv, isbf);
                int o = rowl * LDP + col;
                float kv = bf2f(bufB[o]);
                bufB[o] = f2bf(qv - kv);    // same lane wrote it in stage 3
            }
    __syncthreads();

    // ---- stage 5: v = h@Wv -> packed bf16 registers ----
    zero_acc(acc);
    gemm_acc<12, LDP>(bufA, wq_v, ntBase, lane, acc);
    unsigned vpk[2][3][2];
#pragma unroll
    for (int mt = 0; mt < 2; ++mt)
#pragma unroll
        for (int i = 0; i < 3; ++i) {
            vpk[mt][i][0] = (unsigned)f2bf(acc[mt][i][0]) | ((unsigned)f2bf(acc[mt][i][1]) << 16);
            vpk[mt][i][1] = (unsigned)f2bf(acc[mt][i][2]) | ((unsigned)f2bf(acc[mt][i][3]) << 16);
        }
    __syncthreads();                       // h (bufA) free from here

    // ---- stage 6: g1 = gelu(d@Wg1 + bg1) -> bufA ----
    bias_acc(acc, bg1, ntBase, l16, isbf);
    gemm_acc<12, LDP>(bufB, wq_g1, ntBase, lane, acc);
    store_lds(bufA, acc, quad, l16, ntBase, true);
    __syncthreads();

    // ---- stage 7: gate = g1@Wg2 + bg2; row softmax; pv = attn*v -> bufA ----
    bias_acc(acc, bg2, ntBase, l16, isbf);
    gemm_acc<12, LDP>(bufA, wq_g2, ntBase, lane, acc);
    // e = exp(gate*SCALE) (max-free: |gate*SCALE| << 1), partial row sums
#pragma unroll
    for (int mt = 0; mt < 2; ++mt)
#pragma unroll
        for (int r = 0; r < 4; ++r) {
            float p = 0.f;
#pragma unroll
            for (int i = 0; i < 3; ++i) {
                float e = __expf(acc[mt][i][r] * SCALE);
                acc[mt][i][r] = e;
                p += e;
            }
#pragma unroll
            for (int msk = 1; msk < 16; msk <<= 1) p += __shfl_xor(p, msk, 64);
            if (l16 == 0) atomicAdd(&rowsum[mt * 16 + quad * 4 + r], p);
        }
    __syncthreads();                       // sums complete; g1 reads complete
#pragma unroll
    for (int mt = 0; mt < 2; ++mt)
#pragma unroll
        for (int r = 0; r < 4; ++r) {
            int rowl = mt * 16 + quad * 4 + r;
            float inv = 1.f / rowsum[rowl];
#pragma unroll
            for (int i = 0; i < 3; ++i) {
                int col = (ntBase + i) * 16 + l16;
                float vv = bf2f((ushort)(vpk[mt][i][r >> 1] >> ((r & 1) * 16)));
                bufA[rowl * LDP + col] = f2bf(acc[mt][i][r] * inv * vv);
            }
        }
    __syncthreads();

    // ---- stage 8: res = pv@Wout + bout + pre -> global ----
    bias_acc(acc, bout, ntBase, l16, isbf);
    gemm_acc<12, LDP>(bufA, wq_o, ntBase, lane, acc);
#pragma unroll
    for (int mt = 0; mt < 2; ++mt)
#pragma unroll
        for (int i = 0; i < 3; ++i)
#pragma unroll
            for (int r = 0; r < 4; ++r) {
                int rowl = mt * 16 + quad * 4 + r;
                int col  = (ntBase + i) * 16 + l16;
                size_t tok = (size_t)(row0 + rowl);
                float pre = ldg(x, tok * XC + 3 + col, isbf);
                stg(out, (size_t)NTOK * DIMS + tok * DIMS + col,
                    acc[mt][i][r] + pre, isbf);
            }
}

extern "C" void kernel_launch(void* const* d_in, const int* in_sizes, int n_in,
                              void* d_out, int out_size, void* d_ws, size_t ws_size,
                              hipStream_t stream) {
    // setup_inputs order:
    // 0 idx, 1 q(unused), 2 x, 3 W_pos1, 4 b_pos1, 5 W_pos2, 6 b_pos2,
    // 7 W_in, 8 b_in, 9 W_q, 10 W_k, 11 W_v, 12 W_g1, 13 b_g1, 14 W_g2,
    // 15 b_g2, 16 W_out, 17 b_out.
    const void* x     = d_in[2];
    const void* Wpos1 = d_in[3];
    const void* bpos1 = d_in[4];
    const void* Wpos2 = d_in[5];
    const void* bpos2 = d_in[6];
    const void* Win   = d_in[7];
    const void* bin   = d_in[8];
    const void* Wq    = d_in[9];
    const void* Wk    = d_in[10];
    const void* Wv    = d_in[11];
    const void* Wg1   = d_in[12];
    const void* bg1   = d_in[13];
    const void* Wg2   = d_in[14];
    const void* bg2   = d_in[15];
    const void* Wo    = d_in[16];
    const void* bout  = d_in[17];
    ushort* ws  = (ushort*)d_ws;
    int* flag   = (int*)(ws + WS_FLAG_OFF);

    detect_dtype<<<1, 64, 0, stream>>>((const ushort*)x, flag);

    dim3 pgrid(24, 88);
    prep_weights<<<pgrid, 64, 0, stream>>>(Wpos2, Win, Wq, Wk, Wv, Wg1, Wg2, Wo, ws, flag);

    fused_kernel<<<dim3(NTOK / TM), 512, 0, stream>>>(
        x, Wpos1, bpos1, bpos2, bin, bg1, bg2, bout, ws, d_out, flag);
}